// Round 3
// baseline (91.962 us; speedup 1.0000x reference)
//
#include <hip/hip_runtime.h>
#include <stdint.h>

// out[n, m=c*64+i, r] = S * sum_j W[c,r,i,j] * X[n,r,j],  S = DELTA_G*DELTA_V
// N=4096, M=1024 (c=16 x i=64), R=16, K=64.  GMIN terms cancel exactly.
//
// Round-3 design: NO X staging (X read direct from global/L2 into B-frags,
// cvt in-reg: each element consumed exactly once per block, so staging was
// pure overhead). LDS holds only the output-transpose tile (16n x 514dw =
// 32.9 KB) -> 3-4 blocks/CU, 2 barriers/iter. W A-frags hoisted to regs once.
// Pitch 514 (=2 mod 32) makes both ep1 float2 writes and ep2 float2 reads
// conflict-free (16 bank-pairs x 4 lanes = 4-phase minimum).

using bf16x8 = __attribute__((ext_vector_type(8))) short;
using f32x4  = __attribute__((ext_vector_type(4))) float;
using f32x2  = __attribute__((ext_vector_type(2))) float;

#define PITCH_DW 514                  // dwords per n-row: 512 data + 2 pad
#define LDS_BYTES (16 * PITCH_DW * 4) // 32896

__device__ inline ushort f2bf(float f) {
  uint32_t u = __builtin_bit_cast(uint32_t, f);
  u += 0x7FFFu + ((u >> 16) & 1u);    // RNE (inputs finite)
  return (ushort)(u >> 16);
}

__device__ inline bf16x8 cvt8v(float4 a, float4 b) {
  union { bf16x8 v; ushort u[8]; } r;
  r.u[0] = f2bf(a.x); r.u[1] = f2bf(a.y); r.u[2] = f2bf(a.z); r.u[3] = f2bf(a.w);
  r.u[4] = f2bf(b.x); r.u[5] = f2bf(b.y); r.u[6] = f2bf(b.z); r.u[7] = f2bf(b.w);
  return r.v;
}

__global__ __launch_bounds__(512, 6)
void crxb_kernel(const float* __restrict__ X, const float* __restrict__ W,
                 float* __restrict__ out) {
  extern __shared__ char smem[];
  float* O = (float*)smem;            // [n 0..15][514 dwords]

  const int t   = threadIdx.x;
  const int bid = blockIdx.x;
  // 1024 blocks = 32 m-tiles x 32 n-groups (128 n each). XCD-aware: all 32
  // m-blocks of one n-group land on the same XCD (bid%8) -> X slice (2 MB)
  // stays in that XCD's L2.
  const int xcd  = bid & 7;
  const int slot = bid >> 3;          // 0..127
  const int ng   = xcd * 4 + (slot & 3);   // 0..31
  const int mt   = slot >> 2;              // 0..31
  const int c  = mt >> 1;
  const int i0 = (mt & 1) << 5;
  const int m0 = mt << 5;

  const int wid = t >> 6;
  const int l   = t & 63;
  const int lr  = l & 15;             // A row (m within 16) / B col (n)
  const int lk  = l >> 4;             // k-subgroup 0..3
  const int r0w = wid << 1;           // wave owns r0w, r0w+1

  // ---- hoist A fragments: W fp32 global -> bf16 regs (once per block) ----
  bf16x8 A[2][2][2];                  // [rr][ks][a]
  #pragma unroll
  for (int rr = 0; rr < 2; ++rr)
    #pragma unroll
    for (int ks = 0; ks < 2; ++ks)
      #pragma unroll
      for (int a = 0; a < 2; ++a) {
        const float* gw = W + (((size_t)(c * 16 + r0w + rr) * 64) + (i0 + a * 16 + lr)) * 64
                            + ks * 32 + lk * 8;
        A[rr][ks][a] = cvt8v(*(const float4*)gw, *(const float4*)(gw + 4));
      }

  const float S = (float)((0.000333 - 3.33e-07) * (3.3 / 255.0));

  for (int it = 0; it < 8; ++it) {
    const int n0 = ng * 128 + it * 16;

    // ---- compute: B-frags straight from global (L2-hit), cvt in-reg ----
    f32x4 acc[2][2];                  // [rr][a]
    #pragma unroll
    for (int rr = 0; rr < 2; ++rr)
      #pragma unroll
      for (int a = 0; a < 2; ++a) acc[rr][a] = (f32x4){0.f, 0.f, 0.f, 0.f};

    #pragma unroll
    for (int rr = 0; rr < 2; ++rr) {
      const float* xb = X + (size_t)(n0 + lr) * 1024 + (r0w + rr) * 64;
      #pragma unroll
      for (int ks = 0; ks < 2; ++ks) {
        float4 xa = *(const float4*)(xb + ks * 32 + lk * 8);
        float4 xc = *(const float4*)(xb + ks * 32 + lk * 8 + 4);
        bf16x8 Bf = cvt8v(xa, xc);
        acc[rr][0] = __builtin_amdgcn_mfma_f32_16x16x32_bf16(A[rr][ks][0], Bf, acc[rr][0], 0, 0, 0);
        acc[rr][1] = __builtin_amdgcn_mfma_f32_16x16x32_bf16(A[rr][ks][1], Bf, acc[rr][1], 0, 0, 0);
      }
    }

    __syncthreads();                  // prev iter's ep2 reads of O complete

    // ---- ep1: acc*S -> O, r-paired float2 (conflict-free: 16 bank-pairs) ----
    #pragma unroll
    for (int a = 0; a < 2; ++a)
      #pragma unroll
      for (int reg = 0; reg < 4; ++reg) {
        f32x2 v = {acc[0][a][reg] * S, acc[1][a][reg] * S};
        const int mm = a * 16 + lk * 4 + reg;     // m within 32
        *(f32x2*)(O + (size_t)lr * PITCH_DW + mm * 16 + r0w) = v;
      }
    __syncthreads();

    // ---- ep2: O -> global, coalesced float2 runs (nontemporal, never re-read) ----
    {
      const int n  = t >> 5;          // 0..15
      const int j0 = t & 31;
      const float* Or = O + (size_t)n * PITCH_DW;
      float* gout = out + ((size_t)(n0 + n)) * 16384 + (size_t)m0 * 16;
      #pragma unroll
      for (int q = 0; q < 8; ++q) {
        const int u = (q * 32 + j0) * 2;          // dword offset, 0..1022
        f32x2 v = *(const f32x2*)(Or + u);
        __builtin_nontemporal_store(v, (f32x2*)(gout + u));
      }
    }
  }
}

extern "C" void kernel_launch(void* const* d_in, const int* in_sizes, int n_in,
                              void* d_out, int out_size, void* d_ws, size_t ws_size,
                              hipStream_t stream) {
  const float* X = (const float*)d_in[0];   // [4096,1,16,64,1]
  const float* W = (const float*)d_in[1];   // [16,16,64,64]
  float* out = (float*)d_out;               // [4096,1024,16]
  (void)in_sizes; (void)n_in; (void)d_ws; (void)ws_size; (void)out_size;

  hipFuncSetAttribute(reinterpret_cast<const void*>(crxb_kernel),
                      hipFuncAttributeMaxDynamicSharedMemorySize, LDS_BYTES);

  crxb_kernel<<<dim3(1024), dim3(512), LDS_BYTES, stream>>>(X, W, out);
}

// Round 5
// 72.537 us; speedup vs baseline: 1.2678x; 1.2678x over previous
//
#include <hip/hip_runtime.h>
#include <stdint.h>

// out[n, m=c*64+i, r] = S * sum_j W[c,r,i,j] * X[n,r,j],  S = DELTA_G*DELTA_V
// N=4096, M=1024 (c=16 x i=64), R=16, K=64.  GMIN terms cancel exactly.
//
// Round-5 = round-4 with the nontemporal-store type fixed (ext-vector f32x4,
// not HIP_vector_type float4 which the builtin rejects).
//  - __syncthreads() -> s_waitcnt lgkmcnt(0); s_barrier  (NO vmcnt drain):
//    stores stay in flight across barriers, draining at HBM rate under the
//    next compute/stage phase.
//  - XCD-aware block mapping (all 32 m-blocks of one n-group on one XCD).
//  - nontemporal ep2 stores (output never re-read).
//  - grid 1024 x NIT=8: 2-round schedule staggers co-resident block phases.

using bf16x8 = __attribute__((ext_vector_type(8))) short;
using f32x4  = __attribute__((ext_vector_type(4))) float;
using f32x2  = __attribute__((ext_vector_type(2))) float;

#define NPT 16               // n per iteration tile (MFMA N-dim requires 16)
#define NIT 8                // iterations per block (8*16 = 128 n per block)
#define PITCH_B 2064         // bytes per n-row in LDS (516 dwords)
#define BUFB 33024           // 16 rows * 2064
#define LDS_BYTES (2*BUFB)   // 66048: double buffer -> 2 blocks/CU

// LDS-only barrier: order ds ops across waves without draining the VM queue.
#define BARRIER() asm volatile("s_waitcnt lgkmcnt(0)\n\ts_barrier" ::: "memory")

__device__ inline ushort f2bf(float f) {
  uint32_t u = __builtin_bit_cast(uint32_t, f);
  u += 0x7FFFu + ((u >> 16) & 1u);   // RNE (inputs finite)
  return (ushort)(u >> 16);
}

__device__ inline bf16x8 cvt8v(float4 a, float4 b) {
  union { bf16x8 v; ushort u[8]; } r;
  r.u[0] = f2bf(a.x); r.u[1] = f2bf(a.y); r.u[2] = f2bf(a.z); r.u[3] = f2bf(a.w);
  r.u[4] = f2bf(b.x); r.u[5] = f2bf(b.y); r.u[6] = f2bf(b.z); r.u[7] = f2bf(b.w);
  return r.v;
}

__global__ __launch_bounds__(512, 4)
void crxb_kernel(const float* __restrict__ X, const float* __restrict__ W,
                 float* __restrict__ out) {
  extern __shared__ char smem[];
  const int t   = threadIdx.x;
  const int bid = blockIdx.x;
  // 1024 blocks = 32 m-tiles x 32 n-groups (128 n each). XCD-aware: all 32
  // m-blocks of one n-group land on one XCD (bid%8) -> X slice L2-resident.
  const int xcd  = bid & 7;
  const int ng   = xcd * 4 + ((bid >> 3) & 3);  // 0..31
  const int mt   = bid >> 5;                    // 0..31
  const int c  = mt >> 1;
  const int i0 = (mt & 1) << 5;
  const int m0 = mt << 5;

  const int wid = t >> 6;
  const int l   = t & 63;
  const int lr  = l & 15;            // A row (m within 16) / B col (n)
  const int lk  = l >> 4;            // k-subgroup 0..3
  const int r0w = wid << 1;          // wave owns r0w, r0w+1

  // ---- hoist A fragments: W fp32 global -> bf16 regs (once per block) ----
  bf16x8 A[2][2][2];                 // [rr][ks][a]
  #pragma unroll
  for (int rr = 0; rr < 2; ++rr)
    #pragma unroll
    for (int ks = 0; ks < 2; ++ks)
      #pragma unroll
      for (int a = 0; a < 2; ++a) {
        const float* gw = W + (((size_t)(c * 16 + r0w + rr) * 64) + (i0 + a * 16 + lr)) * 64
                            + ks * 32 + lk * 8;
        A[rr][ks][a] = cvt8v(*(const float4*)gw, *(const float4*)(gw + 4));
      }

  const float S = (float)((0.000333 - 3.33e-07) * (3.3 / 255.0));

  // ---- prologue: stage X tile 0 into buf0 ----
  {
    #pragma unroll
    for (int p = 0; p < 4; ++p) {
      int u = p * 512 + t;                     // 0..2047 bf16x8 units
      int n = u >> 7, r = (u >> 3) & 15, k8 = u & 7;
      const float* gx = X + (((size_t)(ng * 128 + n) * 16) + r) * 64 + k8 * 8;
      *(bf16x8*)(smem + (size_t)n * PITCH_B + r * 128 + k8 * 16) =
          cvt8v(*(const float4*)gx, *(const float4*)(gx + 4));
    }
  }
  BARRIER();

  int cur = 0;
  for (int it = 0; it < NIT; ++it) {
    char* bufc = smem + cur * BUFB;
    char* bufn = smem + (cur ^ 1) * BUFB;
    const int n0 = ng * 128 + it * NPT;

    // ---- issue next-tile X loads early (hide HBM/L2 latency under compute) ----
    float4 xp[8];
    if (it + 1 < NIT) {
      #pragma unroll
      for (int p = 0; p < 4; ++p) {
        int u = p * 512 + t;
        int n = u >> 7, r = (u >> 3) & 15, k8 = u & 7;
        const float* gx = X + (((size_t)(n0 + NPT + n) * 16) + r) * 64 + k8 * 8;
        xp[2 * p]     = *(const float4*)gx;
        xp[2 * p + 1] = *(const float4*)(gx + 4);
      }
    }

    // ---- compute: 32m x 16n, 2 r's per wave, 8 MFMAs ----
    f32x4 acc[2][2];                 // [rr][a]
    #pragma unroll
    for (int rr = 0; rr < 2; ++rr)
      #pragma unroll
      for (int a = 0; a < 2; ++a) acc[rr][a] = (f32x4){0.f, 0.f, 0.f, 0.f};

    #pragma unroll
    for (int rr = 0; rr < 2; ++rr) {
      const int r = r0w + rr;
      #pragma unroll
      for (int ks = 0; ks < 2; ++ks) {
        bf16x8 Bf = *(const bf16x8*)(bufc + (size_t)lr * PITCH_B + r * 128 + ks * 64 + lk * 16);
        acc[rr][0] = __builtin_amdgcn_mfma_f32_16x16x32_bf16(A[rr][ks][0], Bf, acc[rr][0], 0, 0, 0);
        acc[rr][1] = __builtin_amdgcn_mfma_f32_16x16x32_bf16(A[rr][ks][1], Bf, acc[rr][1], 0, 0, 0);
      }
    }
    BARRIER();                       // all reads of bufc done (LDS order only)

    // ---- ep1: acc*S -> O (fp32) in bufc; r-paired float2 stores ----
    #pragma unroll
    for (int a = 0; a < 2; ++a)
      #pragma unroll
      for (int reg = 0; reg < 4; ++reg) {
        f32x2 v = {acc[0][a][reg] * S, acc[1][a][reg] * S};
        const int mm = a * 16 + lk * 4 + reg;     // m within 32
        *(f32x2*)(bufc + ((size_t)lr * 516 + mm * 16 + r0w) * 4) = v;
      }
    BARRIER();

    // ---- ep2: O -> global, coalesced nontemporal stores (stay in flight) ----
    {
      const int n  = t >> 5;         // 0..15
      const int j0 = t & 31;
      const float* Or = (const float*)(bufc + (size_t)n * PITCH_B);
      float* gout = out + ((size_t)(n0 + n)) * 16384 + (size_t)m0 * 16;
      #pragma unroll
      for (int q = 0; q < 4; ++q) {
        const int u = (q * 32 + j0) * 4;          // dword offset
        f32x4 v = *(const f32x4*)(Or + u);
        __builtin_nontemporal_store(v, (f32x4*)(gout + u));
      }
    }

    // ---- stage next tile: cvt prefetched regs -> bufn ----
    if (it + 1 < NIT) {
      #pragma unroll
      for (int p = 0; p < 4; ++p) {
        int u = p * 512 + t;
        int n = u >> 7, r = (u >> 3) & 15, k8 = u & 7;
        *(bf16x8*)(bufn + (size_t)n * PITCH_B + r * 128 + k8 * 16) = cvt8v(xp[2 * p], xp[2 * p + 1]);
      }
    }
    BARRIER();
    cur ^= 1;
  }
}

extern "C" void kernel_launch(void* const* d_in, const int* in_sizes, int n_in,
                              void* d_out, int out_size, void* d_ws, size_t ws_size,
                              hipStream_t stream) {
  const float* X = (const float*)d_in[0];   // [4096,1,16,64,1]
  const float* W = (const float*)d_in[1];   // [16,16,64,64]
  float* out = (float*)d_out;               // [4096,1024,16]
  (void)in_sizes; (void)n_in; (void)d_ws; (void)ws_size; (void)out_size;

  (void)hipFuncSetAttribute(reinterpret_cast<const void*>(crxb_kernel),
                            hipFuncAttributeMaxDynamicSharedMemorySize, LDS_BYTES);

  crxb_kernel<<<dim3(1024), dim3(512), LDS_BYTES, stream>>>(X, W, out);
}

// Round 6
// 62.000 us; speedup vs baseline: 1.4833x; 1.1700x over previous
//
#include <hip/hip_runtime.h>
#include <hip/hip_bf16.h>
#include <stdint.h>

// out[n, m=c*64+i, r] = S * sum_j W[c,r,i,j] * X[n,r,j],  S = DELTA_G*DELTA_V
// N=4096, M=1024 (c=16 x i=64), R=16, K=64.  GMIN terms cancel exactly.
//
// Round-6 = EXACT round-2 structure (proven 61.5us: grid 512, NIT=16, normal
// float4 stores, round-2 XCD map) with ONE change, A/B-isolated:
//   __syncthreads() -> s_waitcnt lgkmcnt(0); s_barrier   (no vmcnt(0) drain)
// so ep2's global stores stay in flight across the 3 per-iter barriers and
// retire under the next compute/stage phase instead of serially.

using bf16x8 = __attribute__((ext_vector_type(8))) short;
using f32x4  = __attribute__((ext_vector_type(4))) float;
using f32x2  = __attribute__((ext_vector_type(2))) float;

#define NPT 16               // n per iteration tile
#define NIT 16               // iterations per block (16*16 = 256 n per block)
#define PITCH_B 2064         // bytes per n-row in LDS (516 dwords)
#define BUFB 33024           // 16 rows * 2064
#define LDS_BYTES (2*BUFB)   // 66048: double buffer -> 2 blocks/CU

// LDS-only barrier: order ds ops across waves without draining the VM queue.
#define BARRIER() asm volatile("s_waitcnt lgkmcnt(0)\n\ts_barrier" ::: "memory")

__device__ inline ushort f2bf(float f) {
  uint32_t u = __builtin_bit_cast(uint32_t, f);
  u += 0x7FFFu + ((u >> 16) & 1u);   // RNE (inputs finite)
  return (ushort)(u >> 16);
}

__device__ inline bf16x8 cvt8v(float4 a, float4 b) {
  union { bf16x8 v; ushort u[8]; } r;
  r.u[0] = f2bf(a.x); r.u[1] = f2bf(a.y); r.u[2] = f2bf(a.z); r.u[3] = f2bf(a.w);
  r.u[4] = f2bf(b.x); r.u[5] = f2bf(b.y); r.u[6] = f2bf(b.z); r.u[7] = f2bf(b.w);
  return r.v;
}

__global__ __launch_bounds__(512, 4)
void crxb_kernel(const float* __restrict__ X, const float* __restrict__ W,
                 float* __restrict__ out) {
  extern __shared__ char smem[];
  const int t   = threadIdx.x;
  const int bid = blockIdx.x;
  // XCD-aware mapping (round-2): each XCD owns 2 n-groups; all 32 m-tiles of a
  // given n-group land on the same XCD -> X slice stays in that XCD's L2.
  const int ngrp = ((bid & 7) << 1) | ((bid >> 3) & 1);  // 0..15, 256 n each
  const int mt   = bid >> 4;                             // 0..31
  const int c  = mt >> 1;
  const int i0 = (mt & 1) << 5;
  const int m0 = mt << 5;

  const int wid = t >> 6;
  const int l   = t & 63;
  const int lr  = l & 15;            // A row (m within 16) / B col (n)
  const int lk  = l >> 4;            // k-subgroup 0..3
  const int r0w = wid << 1;          // wave owns r0w, r0w+1

  // ---- hoist A fragments: W fp32 global -> bf16 regs (once per block) ----
  bf16x8 A[2][2][2];                 // [rr][ks][a]
  #pragma unroll
  for (int rr = 0; rr < 2; ++rr)
    #pragma unroll
    for (int ks = 0; ks < 2; ++ks)
      #pragma unroll
      for (int a = 0; a < 2; ++a) {
        const float* gw = W + (((size_t)(c * 16 + r0w + rr) * 64) + (i0 + a * 16 + lr)) * 64
                            + ks * 32 + lk * 8;
        A[rr][ks][a] = cvt8v(*(const float4*)gw, *(const float4*)(gw + 4));
      }

  const float S = (float)((0.000333 - 3.33e-07) * (3.3 / 255.0));

  // ---- prologue: stage X tile 0 into buf0 ----
  {
    #pragma unroll
    for (int p = 0; p < 4; ++p) {
      int u = p * 512 + t;                     // 0..2047 bf16x8 units
      int n = u >> 7, r = (u >> 3) & 15, k8 = u & 7;
      const float* gx = X + (((size_t)(ngrp * 256 + n) * 16) + r) * 64 + k8 * 8;
      *(bf16x8*)(smem + (size_t)n * PITCH_B + r * 128 + k8 * 16) =
          cvt8v(*(const float4*)gx, *(const float4*)(gx + 4));
    }
  }
  BARRIER();

  int cur = 0;
  for (int it = 0; it < NIT; ++it) {
    char* bufc = smem + cur * BUFB;
    char* bufn = smem + (cur ^ 1) * BUFB;
    const int n0 = ngrp * 256 + it * NPT;

    // ---- issue next-tile X loads early (latency hides under compute+epilogue) ----
    float4 xp[8];
    if (it + 1 < NIT) {
      #pragma unroll
      for (int p = 0; p < 4; ++p) {
        int u = p * 512 + t;
        int n = u >> 7, r = (u >> 3) & 15, k8 = u & 7;
        const float* gx = X + (((size_t)(n0 + NPT + n) * 16) + r) * 64 + k8 * 8;
        xp[2 * p]     = *(const float4*)gx;
        xp[2 * p + 1] = *(const float4*)(gx + 4);
      }
    }

    // ---- compute: 32m x 16n, 2 r's per wave, 8 MFMAs ----
    f32x4 acc[2][2];                 // [rr][a]
    #pragma unroll
    for (int rr = 0; rr < 2; ++rr)
      #pragma unroll
      for (int a = 0; a < 2; ++a) acc[rr][a] = (f32x4){0.f, 0.f, 0.f, 0.f};

    #pragma unroll
    for (int rr = 0; rr < 2; ++rr) {
      const int r = r0w + rr;
      #pragma unroll
      for (int ks = 0; ks < 2; ++ks) {
        bf16x8 Bf = *(const bf16x8*)(bufc + (size_t)lr * PITCH_B + r * 128 + ks * 64 + lk * 16);
        acc[rr][0] = __builtin_amdgcn_mfma_f32_16x16x32_bf16(A[rr][ks][0], Bf, acc[rr][0], 0, 0, 0);
        acc[rr][1] = __builtin_amdgcn_mfma_f32_16x16x32_bf16(A[rr][ks][1], Bf, acc[rr][1], 0, 0, 0);
      }
    }
    BARRIER();                       // all reads of bufc done (LDS order only)

    // ---- ep1: acc*S -> O (fp32) in bufc; r-paired float2 stores ----
    #pragma unroll
    for (int a = 0; a < 2; ++a)
      #pragma unroll
      for (int reg = 0; reg < 4; ++reg) {
        f32x2 v = {acc[0][a][reg] * S, acc[1][a][reg] * S};
        const int mm = a * 16 + lk * 4 + reg;     // m within 32
        *(f32x2*)(bufc + ((size_t)lr * 516 + mm * 16 + r0w) * 4) = v;
      }
    BARRIER();

    // ---- ep2: O -> global, coalesced float4 stores (normal, as in round 2) ----
    {
      const int n  = t >> 5;         // 0..15
      const int j0 = t & 31;
      const float* Or = (const float*)(bufc + (size_t)n * PITCH_B);
      float* gout = out + ((size_t)(n0 + n)) * 16384 + (size_t)m0 * 16;
      #pragma unroll
      for (int q = 0; q < 4; ++q) {
        const int u = (q * 32 + j0) * 4;          // dword offset
        *(f32x4*)(gout + u) = *(const f32x4*)(Or + u);
      }
    }

    // ---- stage next tile: cvt prefetched regs -> bufn ----
    if (it + 1 < NIT) {
      #pragma unroll
      for (int p = 0; p < 4; ++p) {
        int u = p * 512 + t;
        int n = u >> 7, r = (u >> 3) & 15, k8 = u & 7;
        *(bf16x8*)(bufn + (size_t)n * PITCH_B + r * 128 + k8 * 16) = cvt8v(xp[2 * p], xp[2 * p + 1]);
      }
    }
    BARRIER();
    cur ^= 1;
  }
}

extern "C" void kernel_launch(void* const* d_in, const int* in_sizes, int n_in,
                              void* d_out, int out_size, void* d_ws, size_t ws_size,
                              hipStream_t stream) {
  const float* X = (const float*)d_in[0];   // [4096,1,16,64,1]
  const float* W = (const float*)d_in[1];   // [16,16,64,64]
  float* out = (float*)d_out;               // [4096,1024,16]
  (void)in_sizes; (void)n_in; (void)d_ws; (void)ws_size; (void)out_size;

  (void)hipFuncSetAttribute(reinterpret_cast<const void*>(crxb_kernel),
                            hipFuncAttributeMaxDynamicSharedMemorySize, LDS_BYTES);

  crxb_kernel<<<dim3(512), dim3(512), LDS_BYTES, stream>>>(X, W, out);
}

// Round 7
// 60.475 us; speedup vs baseline: 1.5207x; 1.0252x over previous
//
#include <hip/hip_runtime.h>
#include <hip/hip_bf16.h>
#include <stdint.h>

// out[n, m=c*64+i, r] = S * sum_j W[c,r,i,j] * X[n,r,j],  S = DELTA_G*DELTA_V
// N=4096, M=1024 (c=16 x i=64), R=16, K=64.  GMIN terms cancel exactly.
//
// Round-7 = EXACT round-6 kernel (62.0us: grid 512, NIT=16, light barriers,
// round-2 XCD map) with ONE change, A/B-isolated:
//   ep2 stores -> __builtin_nontemporal_store (no L2 allocate).
// Theory: the 268MB store stream churns the 4MB/XCD L2, evicting the shared
// X slice -> FETCH_SIZE 67MB (~3x ideal). nt stores keep X resident.

using bf16x8 = __attribute__((ext_vector_type(8))) short;
using f32x4  = __attribute__((ext_vector_type(4))) float;
using f32x2  = __attribute__((ext_vector_type(2))) float;

#define NPT 16               // n per iteration tile
#define NIT 16               // iterations per block (16*16 = 256 n per block)
#define PITCH_B 2064         // bytes per n-row in LDS (516 dwords)
#define BUFB 33024           // 16 rows * 2064
#define LDS_BYTES (2*BUFB)   // 66048: double buffer -> 2 blocks/CU

// LDS-only barrier: order ds ops across waves without draining the VM queue.
#define BARRIER() asm volatile("s_waitcnt lgkmcnt(0)\n\ts_barrier" ::: "memory")

__device__ inline ushort f2bf(float f) {
  uint32_t u = __builtin_bit_cast(uint32_t, f);
  u += 0x7FFFu + ((u >> 16) & 1u);   // RNE (inputs finite)
  return (ushort)(u >> 16);
}

__device__ inline bf16x8 cvt8v(float4 a, float4 b) {
  union { bf16x8 v; ushort u[8]; } r;
  r.u[0] = f2bf(a.x); r.u[1] = f2bf(a.y); r.u[2] = f2bf(a.z); r.u[3] = f2bf(a.w);
  r.u[4] = f2bf(b.x); r.u[5] = f2bf(b.y); r.u[6] = f2bf(b.z); r.u[7] = f2bf(b.w);
  return r.v;
}

__global__ __launch_bounds__(512, 4)
void crxb_kernel(const float* __restrict__ X, const float* __restrict__ W,
                 float* __restrict__ out) {
  extern __shared__ char smem[];
  const int t   = threadIdx.x;
  const int bid = blockIdx.x;
  // XCD-aware mapping (round-2): each XCD owns 2 n-groups; all 32 m-tiles of a
  // given n-group land on the same XCD -> X slice stays in that XCD's L2.
  const int ngrp = ((bid & 7) << 1) | ((bid >> 3) & 1);  // 0..15, 256 n each
  const int mt   = bid >> 4;                             // 0..31
  const int c  = mt >> 1;
  const int i0 = (mt & 1) << 5;
  const int m0 = mt << 5;

  const int wid = t >> 6;
  const int l   = t & 63;
  const int lr  = l & 15;            // A row (m within 16) / B col (n)
  const int lk  = l >> 4;            // k-subgroup 0..3
  const int r0w = wid << 1;          // wave owns r0w, r0w+1

  // ---- hoist A fragments: W fp32 global -> bf16 regs (once per block) ----
  bf16x8 A[2][2][2];                 // [rr][ks][a]
  #pragma unroll
  for (int rr = 0; rr < 2; ++rr)
    #pragma unroll
    for (int ks = 0; ks < 2; ++ks)
      #pragma unroll
      for (int a = 0; a < 2; ++a) {
        const float* gw = W + (((size_t)(c * 16 + r0w + rr) * 64) + (i0 + a * 16 + lr)) * 64
                            + ks * 32 + lk * 8;
        A[rr][ks][a] = cvt8v(*(const float4*)gw, *(const float4*)(gw + 4));
      }

  const float S = (float)((0.000333 - 3.33e-07) * (3.3 / 255.0));

  // ---- prologue: stage X tile 0 into buf0 ----
  {
    #pragma unroll
    for (int p = 0; p < 4; ++p) {
      int u = p * 512 + t;                     // 0..2047 bf16x8 units
      int n = u >> 7, r = (u >> 3) & 15, k8 = u & 7;
      const float* gx = X + (((size_t)(ngrp * 256 + n) * 16) + r) * 64 + k8 * 8;
      *(bf16x8*)(smem + (size_t)n * PITCH_B + r * 128 + k8 * 16) =
          cvt8v(*(const float4*)gx, *(const float4*)(gx + 4));
    }
  }
  BARRIER();

  int cur = 0;
  for (int it = 0; it < NIT; ++it) {
    char* bufc = smem + cur * BUFB;
    char* bufn = smem + (cur ^ 1) * BUFB;
    const int n0 = ngrp * 256 + it * NPT;

    // ---- issue next-tile X loads early (latency hides under compute+epilogue) ----
    float4 xp[8];
    if (it + 1 < NIT) {
      #pragma unroll
      for (int p = 0; p < 4; ++p) {
        int u = p * 512 + t;
        int n = u >> 7, r = (u >> 3) & 15, k8 = u & 7;
        const float* gx = X + (((size_t)(n0 + NPT + n) * 16) + r) * 64 + k8 * 8;
        xp[2 * p]     = *(const float4*)gx;
        xp[2 * p + 1] = *(const float4*)(gx + 4);
      }
    }

    // ---- compute: 32m x 16n, 2 r's per wave, 8 MFMAs ----
    f32x4 acc[2][2];                 // [rr][a]
    #pragma unroll
    for (int rr = 0; rr < 2; ++rr)
      #pragma unroll
      for (int a = 0; a < 2; ++a) acc[rr][a] = (f32x4){0.f, 0.f, 0.f, 0.f};

    #pragma unroll
    for (int rr = 0; rr < 2; ++rr) {
      const int r = r0w + rr;
      #pragma unroll
      for (int ks = 0; ks < 2; ++ks) {
        bf16x8 Bf = *(const bf16x8*)(bufc + (size_t)lr * PITCH_B + r * 128 + ks * 64 + lk * 16);
        acc[rr][0] = __builtin_amdgcn_mfma_f32_16x16x32_bf16(A[rr][ks][0], Bf, acc[rr][0], 0, 0, 0);
        acc[rr][1] = __builtin_amdgcn_mfma_f32_16x16x32_bf16(A[rr][ks][1], Bf, acc[rr][1], 0, 0, 0);
      }
    }
    BARRIER();                       // all reads of bufc done (LDS order only)

    // ---- ep1: acc*S -> O (fp32) in bufc; r-paired float2 stores ----
    #pragma unroll
    for (int a = 0; a < 2; ++a)
      #pragma unroll
      for (int reg = 0; reg < 4; ++reg) {
        f32x2 v = {acc[0][a][reg] * S, acc[1][a][reg] * S};
        const int mm = a * 16 + lk * 4 + reg;     // m within 32
        *(f32x2*)(bufc + ((size_t)lr * 516 + mm * 16 + r0w) * 4) = v;
      }
    BARRIER();

    // ---- ep2: O -> global, coalesced NONTEMPORAL float4 stores ----
    {
      const int n  = t >> 5;         // 0..15
      const int j0 = t & 31;
      const float* Or = (const float*)(bufc + (size_t)n * PITCH_B);
      float* gout = out + ((size_t)(n0 + n)) * 16384 + (size_t)m0 * 16;
      #pragma unroll
      for (int q = 0; q < 4; ++q) {
        const int u = (q * 32 + j0) * 4;          // dword offset
        f32x4 v = *(const f32x4*)(Or + u);
        __builtin_nontemporal_store(v, (f32x4*)(gout + u));
      }
    }

    // ---- stage next tile: cvt prefetched regs -> bufn ----
    if (it + 1 < NIT) {
      #pragma unroll
      for (int p = 0; p < 4; ++p) {
        int u = p * 512 + t;
        int n = u >> 7, r = (u >> 3) & 15, k8 = u & 7;
        *(bf16x8*)(bufn + (size_t)n * PITCH_B + r * 128 + k8 * 16) = cvt8v(xp[2 * p], xp[2 * p + 1]);
      }
    }
    BARRIER();
    cur ^= 1;
  }
}

extern "C" void kernel_launch(void* const* d_in, const int* in_sizes, int n_in,
                              void* d_out, int out_size, void* d_ws, size_t ws_size,
                              hipStream_t stream) {
  const float* X = (const float*)d_in[0];   // [4096,1,16,64,1]
  const float* W = (const float*)d_in[1];   // [16,16,64,64]
  float* out = (float*)d_out;               // [4096,1024,16]
  (void)in_sizes; (void)n_in; (void)d_ws; (void)ws_size; (void)out_size;

  (void)hipFuncSetAttribute(reinterpret_cast<const void*>(crxb_kernel),
                            hipFuncAttributeMaxDynamicSharedMemorySize, LDS_BYTES);

  crxb_kernel<<<dim3(512), dim3(512), LDS_BYTES, stream>>>(X, W, out);
}

// Round 8
// 59.531 us; speedup vs baseline: 1.5448x; 1.0158x over previous
//
#include <hip/hip_runtime.h>
#include <hip/hip_bf16.h>
#include <stdint.h>

// out[n, m=c*64+i, r] = S * sum_j W[c,r,i,j] * X[n,r,j],  S = DELTA_G*DELTA_V
// N=4096, M=1024 (c=16 x i=64), R=16, K=64.  GMIN terms cancel exactly.
//
// Round-8 = round-7 kernel (60.5us: grid 512, NIT=16, light barriers, nt
// stores, round-2 XCD map) with ONE lever: per-iter VALU reduction.
//  (a) fp32->bf16 via __float22bfloat162_rn -> native v_cvt_pk_bf16_f32
//      (RNE in HW), replacing the 3-inst/elem manual bit-twiddle.
//  (b) S folded into the W A-fragments at hoist time (bf16 rel-error is
//      scale-invariant; MFMA accumulates fp32) -> ep1 is a pure copy.

using bf16x8 = __attribute__((ext_vector_type(8))) short;
using f32x4  = __attribute__((ext_vector_type(4))) float;
using f32x2  = __attribute__((ext_vector_type(2))) float;

#define NPT 16               // n per iteration tile
#define NIT 16               // iterations per block (16*16 = 256 n per block)
#define PITCH_B 2064         // bytes per n-row in LDS (516 dwords)
#define BUFB 33024           // 16 rows * 2064
#define LDS_BYTES (2*BUFB)   // 66048: double buffer -> 2 blocks/CU

// LDS-only barrier: order ds ops across waves without draining the VM queue.
#define BARRIER() asm volatile("s_waitcnt lgkmcnt(0)\n\ts_barrier" ::: "memory")

__device__ inline bf16x8 cvt8v(float4 a, float4 b) {
  union { bf16x8 v; __hip_bfloat162 h[4]; } r;
  r.h[0] = __float22bfloat162_rn(float2{a.x, a.y});
  r.h[1] = __float22bfloat162_rn(float2{a.z, a.w});
  r.h[2] = __float22bfloat162_rn(float2{b.x, b.y});
  r.h[3] = __float22bfloat162_rn(float2{b.z, b.w});
  return r.v;
}

__global__ __launch_bounds__(512, 4)
void crxb_kernel(const float* __restrict__ X, const float* __restrict__ W,
                 float* __restrict__ out) {
  extern __shared__ char smem[];
  const int t   = threadIdx.x;
  const int bid = blockIdx.x;
  // XCD-aware mapping: each XCD owns 2 n-groups; all 32 m-tiles of a given
  // n-group land on the same XCD -> X slice stays in that XCD's L2.
  const int ngrp = ((bid & 7) << 1) | ((bid >> 3) & 1);  // 0..15, 256 n each
  const int mt   = bid >> 4;                             // 0..31
  const int c  = mt >> 1;
  const int i0 = (mt & 1) << 5;
  const int m0 = mt << 5;

  const int wid = t >> 6;
  const int l   = t & 63;
  const int lr  = l & 15;            // A row (m within 16) / B col (n)
  const int lk  = l >> 4;            // k-subgroup 0..3
  const int r0w = wid << 1;          // wave owns r0w, r0w+1

  const float S = (float)((0.000333 - 3.33e-07) * (3.3 / 255.0));

  // ---- hoist A fragments: (S*W) fp32 global -> bf16 regs (once per block) ----
  bf16x8 A[2][2][2];                 // [rr][ks][a]
  #pragma unroll
  for (int rr = 0; rr < 2; ++rr)
    #pragma unroll
    for (int ks = 0; ks < 2; ++ks)
      #pragma unroll
      for (int a = 0; a < 2; ++a) {
        const float* gw = W + (((size_t)(c * 16 + r0w + rr) * 64) + (i0 + a * 16 + lr)) * 64
                            + ks * 32 + lk * 8;
        float4 wa = *(const float4*)gw;
        float4 wb = *(const float4*)(gw + 4);
        wa.x *= S; wa.y *= S; wa.z *= S; wa.w *= S;
        wb.x *= S; wb.y *= S; wb.z *= S; wb.w *= S;
        A[rr][ks][a] = cvt8v(wa, wb);
      }

  // ---- prologue: stage X tile 0 into buf0 ----
  {
    #pragma unroll
    for (int p = 0; p < 4; ++p) {
      int u = p * 512 + t;                     // 0..2047 bf16x8 units
      int n = u >> 7, r = (u >> 3) & 15, k8 = u & 7;
      const float* gx = X + (((size_t)(ngrp * 256 + n) * 16) + r) * 64 + k8 * 8;
      *(bf16x8*)(smem + (size_t)n * PITCH_B + r * 128 + k8 * 16) =
          cvt8v(*(const float4*)gx, *(const float4*)(gx + 4));
    }
  }
  BARRIER();

  int cur = 0;
  for (int it = 0; it < NIT; ++it) {
    char* bufc = smem + cur * BUFB;
    char* bufn = smem + (cur ^ 1) * BUFB;
    const int n0 = ngrp * 256 + it * NPT;

    // ---- issue next-tile X loads early (latency hides under compute+epilogue) ----
    float4 xp[8];
    if (it + 1 < NIT) {
      #pragma unroll
      for (int p = 0; p < 4; ++p) {
        int u = p * 512 + t;
        int n = u >> 7, r = (u >> 3) & 15, k8 = u & 7;
        const float* gx = X + (((size_t)(n0 + NPT + n) * 16) + r) * 64 + k8 * 8;
        xp[2 * p]     = *(const float4*)gx;
        xp[2 * p + 1] = *(const float4*)(gx + 4);
      }
    }

    // ---- compute: 32m x 16n, 2 r's per wave, 8 MFMAs ----
    f32x4 acc[2][2];                 // [rr][a]
    #pragma unroll
    for (int rr = 0; rr < 2; ++rr)
      #pragma unroll
      for (int a = 0; a < 2; ++a) acc[rr][a] = (f32x4){0.f, 0.f, 0.f, 0.f};

    #pragma unroll
    for (int rr = 0; rr < 2; ++rr) {
      const int r = r0w + rr;
      #pragma unroll
      for (int ks = 0; ks < 2; ++ks) {
        bf16x8 Bf = *(const bf16x8*)(bufc + (size_t)lr * PITCH_B + r * 128 + ks * 64 + lk * 16);
        acc[rr][0] = __builtin_amdgcn_mfma_f32_16x16x32_bf16(A[rr][ks][0], Bf, acc[rr][0], 0, 0, 0);
        acc[rr][1] = __builtin_amdgcn_mfma_f32_16x16x32_bf16(A[rr][ks][1], Bf, acc[rr][1], 0, 0, 0);
      }
    }
    BARRIER();                       // all reads of bufc done (LDS order only)

    // ---- ep1: acc -> O (fp32) in bufc; r-paired float2 stores (pure copy) ----
    #pragma unroll
    for (int a = 0; a < 2; ++a)
      #pragma unroll
      for (int reg = 0; reg < 4; ++reg) {
        f32x2 v = {acc[0][a][reg], acc[1][a][reg]};
        const int mm = a * 16 + lk * 4 + reg;     // m within 32
        *(f32x2*)(bufc + ((size_t)lr * 516 + mm * 16 + r0w) * 4) = v;
      }
    BARRIER();

    // ---- ep2: O -> global, coalesced NONTEMPORAL float4 stores ----
    {
      const int n  = t >> 5;         // 0..15
      const int j0 = t & 31;
      const float* Or = (const float*)(bufc + (size_t)n * PITCH_B);
      float* gout = out + ((size_t)(n0 + n)) * 16384 + (size_t)m0 * 16;
      #pragma unroll
      for (int q = 0; q < 4; ++q) {
        const int u = (q * 32 + j0) * 4;          // dword offset
        f32x4 v = *(const f32x4*)(Or + u);
        __builtin_nontemporal_store(v, (f32x4*)(gout + u));
      }
    }

    // ---- stage next tile: cvt prefetched regs -> bufn ----
    if (it + 1 < NIT) {
      #pragma unroll
      for (int p = 0; p < 4; ++p) {
        int u = p * 512 + t;
        int n = u >> 7, r = (u >> 3) & 15, k8 = u & 7;
        *(bf16x8*)(bufn + (size_t)n * PITCH_B + r * 128 + k8 * 16) = cvt8v(xp[2 * p], xp[2 * p + 1]);
      }
    }
    BARRIER();
    cur ^= 1;
  }
}

extern "C" void kernel_launch(void* const* d_in, const int* in_sizes, int n_in,
                              void* d_out, int out_size, void* d_ws, size_t ws_size,
                              hipStream_t stream) {
  const float* X = (const float*)d_in[0];   // [4096,1,16,64,1]
  const float* W = (const float*)d_in[1];   // [16,16,64,64]
  float* out = (float*)d_out;               // [4096,1024,16]
  (void)in_sizes; (void)n_in; (void)d_ws; (void)ws_size; (void)out_size;

  (void)hipFuncSetAttribute(reinterpret_cast<const void*>(crxb_kernel),
                            hipFuncAttributeMaxDynamicSharedMemorySize, LDS_BYTES);

  crxb_kernel<<<dim3(512), dim3(512), LDS_BYTES, stream>>>(X, W, out);
}